// Round 4
// baseline (296.648 us; speedup 1.0000x reference)
//
#include <hip/hip_runtime.h>
#include <math.h>

#define M_ROWS 1536
#define NC 96
#define KG 16
#define FD 8192
#define NS 8
#define MARGIN 0.3f

#define KSPLIT 32
#define KCH 256            /* k per block */
#define BKS 32             /* k per stage */
#define BN4 64             /* n cols per block */
#define AST4 36            /* padded LDS strides (floats) */
#define BST4 36

// ---------------- K1: centers + squared-norm partials ----------------
__global__ void centers_kernel(const float* __restrict__ feats,
                               float* __restrict__ centers,
                               float* __restrict__ fnp,   // [4][1536]
                               float* __restrict__ cnp) { // [4][96]
    const int c = blockIdx.x;
    const int bd = blockIdx.y;
    const int tid = threadIdx.x;

    float sq[KG];
#pragma unroll
    for (int k = 0; k < KG; ++k) sq[k] = 0.f;
    float cp = 0.f;

#pragma unroll
    for (int it = 0; it < 2; ++it) {
        const int base = bd * 2048 + it * 1024 + tid * 4;
        float4 acc = make_float4(0.f, 0.f, 0.f, 0.f);
#pragma unroll
        for (int k = 0; k < KG; ++k) {
            const float4 v = *(const float4*)&feats[(size_t)(c * KG + k) * FD + base];
            acc.x += v.x; acc.y += v.y; acc.z += v.z; acc.w += v.w;
            sq[k] += v.x * v.x + v.y * v.y + v.z * v.z + v.w * v.w;
        }
        float4 cv = make_float4(acc.x * 0.0625f, acc.y * 0.0625f,
                                acc.z * 0.0625f, acc.w * 0.0625f);
        *(float4*)&centers[(size_t)c * FD + base] = cv;
        cp += cv.x * cv.x + cv.y * cv.y + cv.z * cv.z + cv.w * cv.w;
    }

    const int lane = tid & 63;
    const int w = tid >> 6;
    __shared__ float wred[4][17];
#pragma unroll
    for (int k = 0; k < KG; ++k) {
        float v = sq[k];
#pragma unroll
        for (int off = 32; off > 0; off >>= 1) v += __shfl_down(v, off, 64);
        if (lane == 0) wred[w][k] = v;
    }
    {
        float v = cp;
#pragma unroll
        for (int off = 32; off > 0; off >>= 1) v += __shfl_down(v, off, 64);
        if (lane == 0) wred[w][16] = v;
    }
    __syncthreads();
    if (tid < 17) {
        const float t = wred[0][tid] + wred[1][tid] + wred[2][tid] + wred[3][tid];
        if (tid < 16) fnp[bd * M_ROWS + c * KG + tid] = t;
        else          cnp[bd * NC + c] = t;
    }
}

// ---------------- K2: dot(center, feat) partial GEMM ----------------
// R2 geometry: 768 blocks, bid = nb*32 + ks, bid%8 == ks%8 pins a k-slice
// to one XCD (centers slice stays L2-resident, feats streamed once).
// Changed vs R2: 256 threads with 6m x 4n per-thread tile (24 acc) to cut
// VGPR from 256 -> ~96 and lift occupancy 2 -> 4 waves/SIMD.
__global__ __launch_bounds__(256, 4) void gemm4_kernel(const float* __restrict__ centers,
                                                       const float* __restrict__ feats,
                                                       float* __restrict__ part) { // [96][32][1536]
    const int bid = blockIdx.x;
    const int ks = bid & 31;
    const int nb = bid >> 5;
    const int tid = threadIdx.x;

    __shared__ float alds[NC * AST4];
    __shared__ float blds[BN4 * BST4];

    const int j0 = nb * BN4;
    const int k0b = ks * KCH;

    const int tx = tid & 15;         // n = tx + 16*nn, nn 0..3
    const int ty = tid >> 4;         // m = ty*6 + mi, mi 0..5
    const int m0 = ty * 6;

    float acc[6][4];
#pragma unroll
    for (int a = 0; a < 6; ++a)
#pragma unroll
        for (int b = 0; b < 4; ++b) acc[a][b] = 0.f;

    for (int st = 0; st < KCH / BKS; ++st) {
        const int k0 = k0b + st * BKS;
        // stage A: 96x32 floats = 768 float4, 3 per thread
#pragma unroll
        for (int i = 0; i < 3; ++i) {
            const int q = tid + i * 256;
            const int m = q >> 3, kk = (q & 7) * 4;
            *(float4*)&alds[m * AST4 + kk] =
                *(const float4*)&centers[(size_t)m * FD + k0 + kk];
        }
        // stage B: 64x32 floats = 512 float4, 2 per thread
#pragma unroll
        for (int i = 0; i < 2; ++i) {
            const int q = tid + i * 256;
            const int n = q >> 3, kk = (q & 7) * 4;
            *(float4*)&blds[n * BST4 + kk] =
                *(const float4*)&feats[(size_t)(j0 + n) * FD + k0 + kk];
        }
        __syncthreads();
#pragma unroll
        for (int kk4 = 0; kk4 < BKS; kk4 += 4) {
            float4 bv[4];
#pragma unroll
            for (int nn = 0; nn < 4; ++nn)
                bv[nn] = *(const float4*)&blds[(tx + nn * 16) * BST4 + kk4];
            float4 av[6];
#pragma unroll
            for (int mi = 0; mi < 6; ++mi)
                av[mi] = *(const float4*)&alds[(m0 + mi) * AST4 + kk4];
#pragma unroll
            for (int mi = 0; mi < 6; ++mi)
#pragma unroll
                for (int nn = 0; nn < 4; ++nn)
                    acc[mi][nn] += av[mi].x * bv[nn].x + av[mi].y * bv[nn].y +
                                   av[mi].z * bv[nn].z + av[mi].w * bv[nn].w;
        }
        __syncthreads();
    }

#pragma unroll
    for (int mi = 0; mi < 6; ++mi) {
        float* row = part + ((size_t)(m0 + mi) * KSPLIT + ks) * M_ROWS + j0;
#pragma unroll
        for (int nn = 0; nn < 4; ++nn)
            row[tx + nn * 16] = acc[mi][nn];
    }
}

// ---------------- K3: finalize d2 + masked argmax/argmin ----------------
__global__ void select_kernel(const float* __restrict__ part,
                              const float* __restrict__ fnp,
                              const float* __restrict__ cnp,
                              const int* __restrict__ labels,
                              int* __restrict__ pinds,
                              int* __restrict__ ninds) {
    const int c = blockIdx.x;
    const int tid = threadIdx.x;
    const int anchor = labels[c * KG];

    float cn = 0.f;
#pragma unroll
    for (int b = 0; b < 4; ++b) cn += cnp[b * NC + c];

    float bestp = -INFINITY; int bpi = 1 << 30;
    float bestn =  INFINITY; int bni = 1 << 30;

    const float* pc = part + (size_t)c * KSPLIT * M_ROWS;
    for (int j = tid; j < M_ROWS; j += 256) {
        float dot = 0.f;
#pragma unroll
        for (int p = 0; p < KSPLIT; ++p)
            dot += pc[(size_t)p * M_ROWS + j];
        float fn = 0.f;
#pragma unroll
        for (int b = 0; b < 4; ++b) fn += fnp[b * M_ROWS + j];
        const float d2 = cn + fn - 2.f * dot;
        const bool pos = (labels[j] == anchor);
        if (pos) {
            if (d2 > bestp || (d2 == bestp && j < bpi)) { bestp = d2; bpi = j; }
        } else {
            if (d2 < bestn || (d2 == bestn && j < bni)) { bestn = d2; bni = j; }
        }
    }

    __shared__ float sv[256];
    __shared__ int   si[256];
    sv[tid] = bestp; si[tid] = bpi; __syncthreads();
    for (int s = 128; s > 0; s >>= 1) {
        if (tid < s) {
            if (sv[tid + s] > sv[tid] ||
                (sv[tid + s] == sv[tid] && si[tid + s] < si[tid])) {
                sv[tid] = sv[tid + s]; si[tid] = si[tid + s];
            }
        }
        __syncthreads();
    }
    if (tid == 0) pinds[c] = si[0];
    __syncthreads();
    sv[tid] = bestn; si[tid] = bni; __syncthreads();
    for (int s = 128; s > 0; s >>= 1) {
        if (tid < s) {
            if (sv[tid + s] < sv[tid] ||
                (sv[tid + s] == sv[tid] && si[tid + s] < si[tid])) {
                sv[tid] = sv[tid + s]; si[tid] = si[tid + s];
            }
        }
        __syncthreads();
    }
    if (tid == 0) ninds[c] = si[0];
}

// ---------------- K4: local stripe distances + DP ----------------
__global__ void local_kernel(const float* __restrict__ centers,
                             const float* __restrict__ localf,
                             const int* __restrict__ pinds,
                             const int* __restrict__ ninds,
                             float* __restrict__ res) { // [2][96]
    const int c = blockIdx.x;
    const int which = blockIdx.y;
    const int tid = threadIdx.x;
    const int idx = (which == 0) ? pinds[c] : ninds[c];

    __shared__ float xl[NS * 1028];
    __shared__ float yl[NS * 1032];
    __shared__ float sred[256];
    __shared__ float dmat[64];
    __shared__ float xx[8], yy[8], xyv[64];

#pragma unroll
    for (int it = 0; it < 8; ++it) {
        const int q = tid + it * 256;
        const float4 v = *(const float4*)&centers[(size_t)c * FD + q * 4];
        const int i = q >> 8;
        const int d = (q * 4) & 1023;
        *(float4*)&xl[i * 1028 + d] = v;

        const float4 w = *(const float4*)&localf[(size_t)idx * FD + q * 4];
        const int jb = (q * 4) & 7;
        const int dd = q >> 1;
        yl[(jb + 0) * 1032 + dd] = w.x;
        yl[(jb + 1) * 1032 + dd] = w.y;
        yl[(jb + 2) * 1032 + dd] = w.z;
        yl[(jb + 3) * 1032 + dd] = w.w;
    }
    __syncthreads();

    const int p = tid >> 2, c4 = tid & 3;
    const int i = p >> 3, j = p & 7;
    float s = 0.f;
    for (int t = 0; t < 64; ++t) {
        const int d = c4 * 4 + t * 16;
        const float4 xv = *(const float4*)&xl[i * 1028 + d];
        const float4 yv = *(const float4*)&yl[j * 1032 + d];
        s += xv.x * yv.x + xv.y * yv.y + xv.z * yv.z + xv.w * yv.w;
    }
    sred[tid] = s;
    __syncthreads();
    if (tid < 64)
        xyv[tid] = sred[tid * 4] + sred[tid * 4 + 1] + sred[tid * 4 + 2] + sred[tid * 4 + 3];

    float s2 = 0.f;
    if (tid < 64) {
        const int r = tid >> 2;
        const float* base = (r < 8) ? &xl[r * 1028] : &yl[(r - 8) * 1032];
        for (int t = 0; t < 64; ++t) {
            const int d = c4 * 4 + t * 16;
            const float4 v = *(const float4*)&base[d];
            s2 += v.x * v.x + v.y * v.y + v.z * v.z + v.w * v.w;
        }
    }
    __syncthreads();
    sred[tid] = s2;
    __syncthreads();
    if (tid < 16) {
        const float v = sred[tid * 4] + sred[tid * 4 + 1] + sred[tid * 4 + 2] + sred[tid * 4 + 3];
        if (tid < 8) xx[tid] = v; else yy[tid - 8] = v;
    }
    __syncthreads();

    if (tid < 64) {
        const float d2 = xx[i] + yy[j] - 2.f * xyv[tid];
        const float d = sqrtf(fmaxf(d2, 1e-12f));
        dmat[tid] = tanhf(0.5f * d);
    }
    __syncthreads();

    if (tid == 0) {
        float prev[8], cur[8];
        cur[0] = dmat[0];
#pragma unroll
        for (int jj = 1; jj < 8; ++jj) cur[jj] = cur[jj - 1] + dmat[jj];
        for (int ii = 1; ii < 8; ++ii) {
#pragma unroll
            for (int jj = 0; jj < 8; ++jj) prev[jj] = cur[jj];
            cur[0] = prev[0] + dmat[ii * 8];
#pragma unroll
            for (int jj = 1; jj < 8; ++jj)
                cur[jj] = fminf(prev[jj], cur[jj - 1]) + dmat[ii * 8 + jj];
        }
        res[which * NC + c] = cur[7];
    }
}

// ---------------- K5: mean(relu(ap - an + margin)) ----------------
__global__ void loss_kernel(const float* __restrict__ res, float* __restrict__ out) {
    const int tid = threadIdx.x; // 128
    float v = 0.f;
    if (tid < NC) v = fmaxf(res[tid] - res[NC + tid] + MARGIN, 0.f);
#pragma unroll
    for (int off = 32; off > 0; off >>= 1) v += __shfl_down(v, off, 64);
    __shared__ float w2[2];
    const int lane = tid & 63, w = tid >> 6;
    if (lane == 0) w2[w] = v;
    __syncthreads();
    if (tid == 0) out[0] = (w2[0] + w2[1]) * (1.f / NC);
}

extern "C" void kernel_launch(void* const* d_in, const int* in_sizes, int n_in,
                              void* d_out, int out_size, void* d_ws, size_t ws_size,
                              hipStream_t stream) {
    const float* feats  = (const float*)d_in[0];
    const int*   labels = (const int*)d_in[1];
    const float* localf = (const float*)d_in[2];
    float* out = (float*)d_out;

    float* centers = (float*)d_ws;                          // 96*8192
    float* part    = centers + (size_t)NC * FD;             // 96*32*1536
    float* fnp     = part + (size_t)NC * KSPLIT * M_ROWS;   // 4*1536
    float* cnp     = fnp + 4 * M_ROWS;                      // 4*96
    float* res     = cnp + 4 * NC;                          // 2*96
    int*   pinds   = (int*)(res + 2 * NC);                  // 96
    int*   ninds   = pinds + NC;                            // 96

    hipLaunchKernelGGL(centers_kernel, dim3(NC, 4), dim3(256), 0, stream,
                       feats, centers, fnp, cnp);
    hipLaunchKernelGGL(gemm4_kernel, dim3(24 * KSPLIT), dim3(256), 0, stream,
                       centers, feats, part);
    hipLaunchKernelGGL(select_kernel, dim3(NC), dim3(256), 0, stream,
                       part, fnp, cnp, labels, pinds, ninds);
    hipLaunchKernelGGL(local_kernel, dim3(NC, 2), dim3(256), 0, stream,
                       centers, localf, pinds, ninds, res);
    hipLaunchKernelGGL(loss_kernel, dim3(1), dim3(128), 0, stream, res, out);
}

// Round 5
// 115.378 us; speedup vs baseline: 2.5711x; 2.5711x over previous
//
#include <hip/hip_runtime.h>
#include <math.h>

#define M_ROWS 1536
#define NC 96
#define KG 16
#define FD 8192
#define NS 8
#define MARGIN 0.3f

#define KSPLIT 32
#define KCH 256            /* k per block */
#define BKS 32             /* k per stage */
#define BN5 64             /* n cols per block */
#define AST5 36            /* padded LDS strides (floats) */
#define BST5 36

// ---------------- K1: centers + squared-norm partials ----------------
__global__ void centers_kernel(const float* __restrict__ feats,
                               float* __restrict__ centers,
                               float* __restrict__ fnp,   // [4][1536]
                               float* __restrict__ cnp) { // [4][96]
    const int c = blockIdx.x;
    const int bd = blockIdx.y;
    const int tid = threadIdx.x;

    float sq[KG];
#pragma unroll
    for (int k = 0; k < KG; ++k) sq[k] = 0.f;
    float cp = 0.f;

#pragma unroll
    for (int it = 0; it < 2; ++it) {
        const int base = bd * 2048 + it * 1024 + tid * 4;
        float4 acc = make_float4(0.f, 0.f, 0.f, 0.f);
#pragma unroll
        for (int k = 0; k < KG; ++k) {
            const float4 v = *(const float4*)&feats[(size_t)(c * KG + k) * FD + base];
            acc.x += v.x; acc.y += v.y; acc.z += v.z; acc.w += v.w;
            sq[k] += v.x * v.x + v.y * v.y + v.z * v.z + v.w * v.w;
        }
        float4 cv = make_float4(acc.x * 0.0625f, acc.y * 0.0625f,
                                acc.z * 0.0625f, acc.w * 0.0625f);
        *(float4*)&centers[(size_t)c * FD + base] = cv;
        cp += cv.x * cv.x + cv.y * cv.y + cv.z * cv.z + cv.w * cv.w;
    }

    const int lane = tid & 63;
    const int w = tid >> 6;
    __shared__ float wred[4][17];
#pragma unroll
    for (int k = 0; k < KG; ++k) {
        float v = sq[k];
#pragma unroll
        for (int off = 32; off > 0; off >>= 1) v += __shfl_down(v, off, 64);
        if (lane == 0) wred[w][k] = v;
    }
    {
        float v = cp;
#pragma unroll
        for (int off = 32; off > 0; off >>= 1) v += __shfl_down(v, off, 64);
        if (lane == 0) wred[w][16] = v;
    }
    __syncthreads();
    if (tid < 17) {
        const float t = wred[0][tid] + wred[1][tid] + wred[2][tid] + wred[3][tid];
        if (tid < 16) fnp[bd * M_ROWS + c * KG + tid] = t;
        else          cnp[bd * NC + c] = t;
    }
}

// ---------------- K2: dot(center, feat) partial GEMM ----------------
// R2 geometry: 768 blocks, bid = nb*32 + ks, bid%8 == ks%8 pins a k-slice
// to one XCD (centers slice stays L2-resident, feats streamed once).
// 256 threads, 6m x 4n acc. NO min-waves launch_bounds arg (R3/R4 lesson:
// it forced VGPR=64 -> scratch spill -> 1.2 GB of HBM traffic).
// Global->reg prefetch pipeline hides HBM/L3 latency under compute.
__global__ __launch_bounds__(256) void gemm5_kernel(const float* __restrict__ centers,
                                                    const float* __restrict__ feats,
                                                    float* __restrict__ part) { // [96][32][1536]
    const int bid = blockIdx.x;
    const int ks = bid & 31;
    const int nb = bid >> 5;
    const int tid = threadIdx.x;

    __shared__ float alds[NC * AST5];
    __shared__ float blds[BN5 * BST5];

    const int j0 = nb * BN5;
    const int k0b = ks * KCH;

    const int tx = tid & 15;         // n = tx + 16*nn, nn 0..3
    const int ty = tid >> 4;         // m = ty*6 + mi, mi 0..5
    const int m0 = ty * 6;

    // staging addresses (constant across stages except k0)
    const int am = tid >> 3;               // A row for this thread's slot 0
    const int akk = (tid & 7) * 4;         // A k-offset within stage
    const int bn = tid >> 3;               // B row slot 0 (q = tid)
    // slot layout: A rows am, am+32, am+64 (q = tid + i*256 -> m = q>>3)
    //              B rows bn, bn+32      (q = tid + i*256 -> n = q>>3)

    float4 pa[3], pb[2];

    {   // prologue: load stage 0
        const int k0 = k0b;
#pragma unroll
        for (int i = 0; i < 3; ++i)
            pa[i] = *(const float4*)&centers[(size_t)(am + i * 32) * FD + k0 + akk];
#pragma unroll
        for (int i = 0; i < 2; ++i)
            pb[i] = *(const float4*)&feats[(size_t)(j0 + bn + i * 32) * FD + k0 + akk];
    }

    float acc[6][4];
#pragma unroll
    for (int a = 0; a < 6; ++a)
#pragma unroll
        for (int b = 0; b < 4; ++b) acc[a][b] = 0.f;

    for (int st = 0; st < KCH / BKS; ++st) {
        // write staged regs to LDS
#pragma unroll
        for (int i = 0; i < 3; ++i)
            *(float4*)&alds[(am + i * 32) * AST5 + akk] = pa[i];
#pragma unroll
        for (int i = 0; i < 2; ++i)
            *(float4*)&blds[(bn + i * 32) * BST5 + akk] = pb[i];
        __syncthreads();

        // issue next stage's global loads (latency overlaps compute below)
        if (st < KCH / BKS - 1) {
            const int k0 = k0b + (st + 1) * BKS;
#pragma unroll
            for (int i = 0; i < 3; ++i)
                pa[i] = *(const float4*)&centers[(size_t)(am + i * 32) * FD + k0 + akk];
#pragma unroll
            for (int i = 0; i < 2; ++i)
                pb[i] = *(const float4*)&feats[(size_t)(j0 + bn + i * 32) * FD + k0 + akk];
        }

#pragma unroll
        for (int kk4 = 0; kk4 < BKS; kk4 += 4) {
            float4 bv[4];
#pragma unroll
            for (int nn = 0; nn < 4; ++nn)
                bv[nn] = *(const float4*)&blds[(tx + nn * 16) * BST5 + kk4];
#pragma unroll
            for (int mi = 0; mi < 6; ++mi) {
                const float4 a = *(const float4*)&alds[(m0 + mi) * AST5 + kk4];
#pragma unroll
                for (int nn = 0; nn < 4; ++nn)
                    acc[mi][nn] += a.x * bv[nn].x + a.y * bv[nn].y +
                                   a.z * bv[nn].z + a.w * bv[nn].w;
            }
        }
        __syncthreads();
    }

#pragma unroll
    for (int mi = 0; mi < 6; ++mi) {
        float* row = part + ((size_t)(m0 + mi) * KSPLIT + ks) * M_ROWS + j0;
#pragma unroll
        for (int nn = 0; nn < 4; ++nn)
            row[tx + nn * 16] = acc[mi][nn];
    }
}

// ---------------- K3: finalize d2 + masked argmax/argmin ----------------
__global__ void select_kernel(const float* __restrict__ part,
                              const float* __restrict__ fnp,
                              const float* __restrict__ cnp,
                              const int* __restrict__ labels,
                              int* __restrict__ pinds,
                              int* __restrict__ ninds) {
    const int c = blockIdx.x;
    const int tid = threadIdx.x;
    const int anchor = labels[c * KG];

    float cn = 0.f;
#pragma unroll
    for (int b = 0; b < 4; ++b) cn += cnp[b * NC + c];

    float bestp = -INFINITY; int bpi = 1 << 30;
    float bestn =  INFINITY; int bni = 1 << 30;

    const float* pc = part + (size_t)c * KSPLIT * M_ROWS;
    for (int j = tid; j < M_ROWS; j += 256) {
        float dot = 0.f;
#pragma unroll
        for (int p = 0; p < KSPLIT; ++p)
            dot += pc[(size_t)p * M_ROWS + j];
        float fn = 0.f;
#pragma unroll
        for (int b = 0; b < 4; ++b) fn += fnp[b * M_ROWS + j];
        const float d2 = cn + fn - 2.f * dot;
        const bool pos = (labels[j] == anchor);
        if (pos) {
            if (d2 > bestp || (d2 == bestp && j < bpi)) { bestp = d2; bpi = j; }
        } else {
            if (d2 < bestn || (d2 == bestn && j < bni)) { bestn = d2; bni = j; }
        }
    }

    __shared__ float sv[256];
    __shared__ int   si[256];
    sv[tid] = bestp; si[tid] = bpi; __syncthreads();
    for (int s = 128; s > 0; s >>= 1) {
        if (tid < s) {
            if (sv[tid + s] > sv[tid] ||
                (sv[tid + s] == sv[tid] && si[tid + s] < si[tid])) {
                sv[tid] = sv[tid + s]; si[tid] = si[tid + s];
            }
        }
        __syncthreads();
    }
    if (tid == 0) pinds[c] = si[0];
    __syncthreads();
    sv[tid] = bestn; si[tid] = bni; __syncthreads();
    for (int s = 128; s > 0; s >>= 1) {
        if (tid < s) {
            if (sv[tid + s] < sv[tid] ||
                (sv[tid + s] == sv[tid] && si[tid + s] < si[tid])) {
                sv[tid] = sv[tid + s]; si[tid] = si[tid + s];
            }
        }
        __syncthreads();
    }
    if (tid == 0) ninds[c] = si[0];
}

// ---------------- K4: local stripe distances + DP ----------------
__global__ void local_kernel(const float* __restrict__ centers,
                             const float* __restrict__ localf,
                             const int* __restrict__ pinds,
                             const int* __restrict__ ninds,
                             float* __restrict__ res) { // [2][96]
    const int c = blockIdx.x;
    const int which = blockIdx.y;
    const int tid = threadIdx.x;
    const int idx = (which == 0) ? pinds[c] : ninds[c];

    __shared__ float xl[NS * 1028];
    __shared__ float yl[NS * 1032];
    __shared__ float sred[256];
    __shared__ float dmat[64];
    __shared__ float xx[8], yy[8], xyv[64];

#pragma unroll
    for (int it = 0; it < 8; ++it) {
        const int q = tid + it * 256;
        const float4 v = *(const float4*)&centers[(size_t)c * FD + q * 4];
        const int i = q >> 8;
        const int d = (q * 4) & 1023;
        *(float4*)&xl[i * 1028 + d] = v;

        const float4 w = *(const float4*)&localf[(size_t)idx * FD + q * 4];
        const int jb = (q * 4) & 7;
        const int dd = q >> 1;
        yl[(jb + 0) * 1032 + dd] = w.x;
        yl[(jb + 1) * 1032 + dd] = w.y;
        yl[(jb + 2) * 1032 + dd] = w.z;
        yl[(jb + 3) * 1032 + dd] = w.w;
    }
    __syncthreads();

    const int p = tid >> 2, c4 = tid & 3;
    const int i = p >> 3, j = p & 7;
    float s = 0.f;
    for (int t = 0; t < 64; ++t) {
        const int d = c4 * 4 + t * 16;
        const float4 xv = *(const float4*)&xl[i * 1028 + d];
        const float4 yv = *(const float4*)&yl[j * 1032 + d];
        s += xv.x * yv.x + xv.y * yv.y + xv.z * yv.z + xv.w * yv.w;
    }
    sred[tid] = s;
    __syncthreads();
    if (tid < 64)
        xyv[tid] = sred[tid * 4] + sred[tid * 4 + 1] + sred[tid * 4 + 2] + sred[tid * 4 + 3];

    float s2 = 0.f;
    if (tid < 64) {
        const int r = tid >> 2;
        const float* base = (r < 8) ? &xl[r * 1028] : &yl[(r - 8) * 1032];
        for (int t = 0; t < 64; ++t) {
            const int d = c4 * 4 + t * 16;
            const float4 v = *(const float4*)&base[d];
            s2 += v.x * v.x + v.y * v.y + v.z * v.z + v.w * v.w;
        }
    }
    __syncthreads();
    sred[tid] = s2;
    __syncthreads();
    if (tid < 16) {
        const float v = sred[tid * 4] + sred[tid * 4 + 1] + sred[tid * 4 + 2] + sred[tid * 4 + 3];
        if (tid < 8) xx[tid] = v; else yy[tid - 8] = v;
    }
    __syncthreads();

    if (tid < 64) {
        const float d2 = xx[i] + yy[j] - 2.f * xyv[tid];
        const float d = sqrtf(fmaxf(d2, 1e-12f));
        dmat[tid] = tanhf(0.5f * d);
    }
    __syncthreads();

    if (tid == 0) {
        float prev[8], cur[8];
        cur[0] = dmat[0];
#pragma unroll
        for (int jj = 1; jj < 8; ++jj) cur[jj] = cur[jj - 1] + dmat[jj];
        for (int ii = 1; ii < 8; ++ii) {
#pragma unroll
            for (int jj = 0; jj < 8; ++jj) prev[jj] = cur[jj];
            cur[0] = prev[0] + dmat[ii * 8];
#pragma unroll
            for (int jj = 1; jj < 8; ++jj)
                cur[jj] = fminf(prev[jj], cur[jj - 1]) + dmat[ii * 8 + jj];
        }
        res[which * NC + c] = cur[7];
    }
}

// ---------------- K5: mean(relu(ap - an + margin)) ----------------
__global__ void loss_kernel(const float* __restrict__ res, float* __restrict__ out) {
    const int tid = threadIdx.x; // 128
    float v = 0.f;
    if (tid < NC) v = fmaxf(res[tid] - res[NC + tid] + MARGIN, 0.f);
#pragma unroll
    for (int off = 32; off > 0; off >>= 1) v += __shfl_down(v, off, 64);
    __shared__ float w2[2];
    const int lane = tid & 63, w = tid >> 6;
    if (lane == 0) w2[w] = v;
    __syncthreads();
    if (tid == 0) out[0] = (w2[0] + w2[1]) * (1.f / NC);
}

extern "C" void kernel_launch(void* const* d_in, const int* in_sizes, int n_in,
                              void* d_out, int out_size, void* d_ws, size_t ws_size,
                              hipStream_t stream) {
    const float* feats  = (const float*)d_in[0];
    const int*   labels = (const int*)d_in[1];
    const float* localf = (const float*)d_in[2];
    float* out = (float*)d_out;

    float* centers = (float*)d_ws;                          // 96*8192
    float* part    = centers + (size_t)NC * FD;             // 96*32*1536
    float* fnp     = part + (size_t)NC * KSPLIT * M_ROWS;   // 4*1536
    float* cnp     = fnp + 4 * M_ROWS;                      // 4*96
    float* res     = cnp + 4 * NC;                          // 2*96
    int*   pinds   = (int*)(res + 2 * NC);                  // 96
    int*   ninds   = pinds + NC;                            // 96

    hipLaunchKernelGGL(centers_kernel, dim3(NC, 4), dim3(256), 0, stream,
                       feats, centers, fnp, cnp);
    hipLaunchKernelGGL(gemm5_kernel, dim3(24 * KSPLIT), dim3(256), 0, stream,
                       centers, feats, part);
    hipLaunchKernelGGL(select_kernel, dim3(NC), dim3(256), 0, stream,
                       part, fnp, cnp, labels, pinds, ninds);
    hipLaunchKernelGGL(local_kernel, dim3(NC, 2), dim3(256), 0, stream,
                       centers, localf, pinds, ninds, res);
    hipLaunchKernelGGL(loss_kernel, dim3(1), dim3(128), 0, stream, res, out);
}